// Round 7
// baseline (387.864 us; speedup 1.0000x reference)
//
#include <hip/hip_runtime.h>

#define NN 8192
#define DDIM 128
#define DELTA 5e-5f
#define MAXC 96

typedef short short8 __attribute__((ext_vector_type(8)));
typedef float f32x16 __attribute__((ext_vector_type(16)));

// ---------------- Kernel 1: MLP (Linear->ReLU->Linear) + L2 normalize ----------------
// FROZEN (bit-exact emb, byte-identical to round-3/5 passing version).
__global__ __launch_bounds__(128, 1)
void mlp_norm_kernel(const float* __restrict__ X, const float* __restrict__ W1,
                     const float* __restrict__ b1, const float* __restrict__ W2,
                     const float* __restrict__ b2, float* __restrict__ emb,
                     int rowsPerBlock)
{
    const int t = threadIdx.x;
    float4 w1r[32], w2r[32];
#pragma unroll
    for (int i = 0; i < 32; ++i) w1r[i] = *(const float4*)&W1[t * DDIM + i * 4];
#pragma unroll
    for (int i = 0; i < 32; ++i) w2r[i] = *(const float4*)&W2[t * DDIM + i * 4];
    const float bb1 = b1[t], bb2 = b2[t];

    __shared__ float sx[DDIM];
    __shared__ float sh[DDIM];
    __shared__ float wred[2];

    const int row0 = blockIdx.x * rowsPerBlock;
    for (int r = 0; r < rowsPerBlock; ++r) {
        const int row = row0 + r;
        sx[t] = X[(size_t)row * DDIM + t];
        __syncthreads();
        float acc = bb1;
#pragma unroll
        for (int i = 0; i < 32; ++i) {
            const float4 xv = *(const float4*)&sx[i * 4];
            acc = fmaf(xv.x, w1r[i].x, acc);
            acc = fmaf(xv.y, w1r[i].y, acc);
            acc = fmaf(xv.z, w1r[i].z, acc);
            acc = fmaf(xv.w, w1r[i].w, acc);
        }
        sh[t] = fmaxf(acc, 0.f);
        __syncthreads();
        float acc2 = bb2;
#pragma unroll
        for (int i = 0; i < 32; ++i) {
            const float4 hv = *(const float4*)&sh[i * 4];
            acc2 = fmaf(hv.x, w2r[i].x, acc2);
            acc2 = fmaf(hv.y, w2r[i].y, acc2);
            acc2 = fmaf(hv.z, w2r[i].z, acc2);
            acc2 = fmaf(hv.w, w2r[i].w, acc2);
        }
        float sq = acc2 * acc2;
#pragma unroll
        for (int off = 1; off < 64; off <<= 1) sq += __shfl_xor(sq, off);
        if ((t & 63) == 0) wred[t >> 6] = sq;
        __syncthreads();
        const float ss = wred[0] + wred[1];
        const float inv = 1.0f / fmaxf(sqrtf(ss), 1e-12f);
        emb[(size_t)row * DDIM + t] = acc2 * inv;
        __syncthreads();   // protect sx/sh/wred for next iteration
    }
}

__device__ __forceinline__ ushort bf16_rne(float v) {
    const unsigned x = __float_as_uint(v);
    return (ushort)((x + 0x7FFFu + ((x >> 16) & 1u)) >> 16);
}

// ---------------- Kernel 2: approx sim = emb @ emb^T via split-bf16 MFMA (3 terms) ----
// emb = H + L (bf16 RNE split, in-register during staging). sim ~= HH^T + HL^T + LH^T.
// Worst-case |approx - exact| <= ~1.1e-5 (unit rows); topk fixup window DELTA=5e-5.
// Block: 256x256 tile, 512 threads = 8 waves (2Mx4N), wave tile 128x64, K-chunks of 32.
// LDS row: 8 x 16B granules (4 hi | 4 lo), XOR-swizzled gr^(row&7), both sides.
__global__ __launch_bounds__(512, 2)
void simgemm_mfma(const float* __restrict__ emb, float* __restrict__ out)
{
    __shared__ ushort ldsA[256 * 64];
    __shared__ ushort ldsB[256 * 64];

    const int tid = threadIdx.x;
    const int bi = blockIdx.x & 31, bj = blockIdx.x >> 5;
    const int m0 = bi << 8, n0 = bj << 8;
    const int lane = tid & 63, wid = tid >> 6;
    const int wr = wid >> 2, wc = wid & 3;
    const int frow = lane & 31, fsel = lane >> 5;

    f32x16 acc[4][2];
#pragma unroll
    for (int mb = 0; mb < 4; ++mb)
#pragma unroll
        for (int nb = 0; nb < 2; ++nb)
#pragma unroll
            for (int q = 0; q < 16; ++q) acc[mb][nb][q] = 0.f;

    const int srow = tid >> 3;
    const int sgr = tid & 7;
    const bool lopart = (sgr & 4) != 0;
    const int skel = (sgr & 3) * 8;

    for (int kc = 0; kc < 4; ++kc) {
        __syncthreads();
#pragma unroll
        for (int i = 0; i < 4; ++i) {
            const int row = srow + i * 64;
            const int woff = row * 64 + ((sgr ^ (row & 7)) << 3);
            {
                const float* p = &emb[(size_t)(m0 + row) * DDIM + kc * 32 + skel];
                ushort g[8];
#pragma unroll
                for (int e = 0; e < 8; ++e) {
                    const float v = p[e];
                    ushort h = bf16_rne(v);
                    if (lopart) h = bf16_rne(v - __uint_as_float((unsigned)h << 16));
                    g[e] = h;
                }
                *(uint4*)&ldsA[woff] = *(const uint4*)g;
            }
            {
                const float* p = &emb[(size_t)(n0 + row) * DDIM + kc * 32 + skel];
                ushort g[8];
#pragma unroll
                for (int e = 0; e < 8; ++e) {
                    const float v = p[e];
                    ushort h = bf16_rne(v);
                    if (lopart) h = bf16_rne(v - __uint_as_float((unsigned)h << 16));
                    g[e] = h;
                }
                *(uint4*)&ldsB[woff] = *(const uint4*)g;
            }
        }
        __syncthreads();
#pragma unroll
        for (int ks = 0; ks < 2; ++ks) {
            const int gh = ks * 2 + fsel;
            short8 ah[4], al[4], bh[2], bl[2];
#pragma unroll
            for (int mb = 0; mb < 4; ++mb) {
                const int r = wr * 128 + mb * 32 + frow;
                ah[mb] = *(const short8*)&ldsA[r * 64 + ((gh ^ (r & 7)) << 3)];
                al[mb] = *(const short8*)&ldsA[r * 64 + (((gh + 4) ^ (r & 7)) << 3)];
            }
#pragma unroll
            for (int nb = 0; nb < 2; ++nb) {
                const int r = wc * 64 + nb * 32 + frow;
                bh[nb] = *(const short8*)&ldsB[r * 64 + ((gh ^ (r & 7)) << 3)];
                bl[nb] = *(const short8*)&ldsB[r * 64 + (((gh + 4) ^ (r & 7)) << 3)];
            }
#pragma unroll
            for (int mb = 0; mb < 4; ++mb)
#pragma unroll
                for (int nb = 0; nb < 2; ++nb) {
                    acc[mb][nb] = __builtin_amdgcn_mfma_f32_32x32x16_bf16(
                        ah[mb], bh[nb], acc[mb][nb], 0, 0, 0);
                    acc[mb][nb] = __builtin_amdgcn_mfma_f32_32x32x16_bf16(
                        ah[mb], bl[nb], acc[mb][nb], 0, 0, 0);
                    acc[mb][nb] = __builtin_amdgcn_mfma_f32_32x32x16_bf16(
                        al[mb], bh[nb], acc[mb][nb], 0, 0, 0);
                }
        }
    }

    // C/D layout: col = lane&31, row = (q&3) + 8*(q>>2) + 4*(lane>>5)  [m74/m101]
#pragma unroll
    for (int mb = 0; mb < 4; ++mb)
#pragma unroll
        for (int nb = 0; nb < 2; ++nb)
#pragma unroll
            for (int q = 0; q < 16; ++q) {
                const int rl = (q & 3) + 8 * (q >> 2) + 4 * fsel;
                const int grow = m0 + wr * 128 + mb * 32 + rl;
                const int gcol = n0 + wc * 64 + nb * 32 + (lane & 31);
                out[(size_t)grow * NN + gcol] = acc[mb][nb][q];
            }
}

// ---------------- Kernel 3: top-kp1 on approx sims + exact fixup + ReLU (in place) ----
// Radix-select kp1-th largest approx value t. Entries > t+DELTA certainly kept (approx
// err <= 1.1e-5). Entries in [t-DELTA, t+DELTA] recomputed EXACTLY (frozen fmaf chain
// from f32 emb, identical to the round-3-proven ordering) and re-ranked.
__global__ __launch_bounds__(256)
void topk_relu_kernel(float* __restrict__ out, const float* __restrict__ emb,
                      const int* __restrict__ kp1p)
{
    const int row = blockIdx.x;
    const int t = threadIdx.x;
    const int w = t >> 6;
    const unsigned kp1 = (unsigned)kp1p[0];
    float* rowp = out + (size_t)row * NN;

    __shared__ unsigned bitmap[NN / 32];   // 1 KB keep-bitmap for window candidates
    __shared__ float semb[DDIM];
    __shared__ unsigned wsum[2][4];
    __shared__ unsigned wmin[4];
    __shared__ int cidx[MAXC];
    __shared__ float cval[MAXC];
    __shared__ int cnum;
    __shared__ unsigned Ash;

    bitmap[t] = 0;
    if (t == 0) { cnum = 0; Ash = 0; }
    if (t < DDIM) semb[t] = emb[(size_t)row * DDIM + t];

    unsigned u[32];
#pragma unroll
    for (int i = 0; i < 8; ++i) {
        const float4 v = *(const float4*)&rowp[(i * 256 + t) * 4];
        u[i * 4 + 0] = v.x > 0.f ? __float_as_uint(v.x) : 0u;
        u[i * 4 + 1] = v.y > 0.f ? __float_as_uint(v.y) : 0u;
        u[i * 4 + 2] = v.z > 0.f ? __float_as_uint(v.z) : 0u;
        u[i * 4 + 3] = v.w > 0.f ? __float_as_uint(v.w) : 0u;
    }

    // ---- radix select kp1-th largest (approx), ballot+popcount, early exit ----
    unsigned thr = 0, teff = 0;
    bool done = false;
    for (int b = 29; b >= 0 && !done; --b) {
        const unsigned cand = thr | (1u << b);
        unsigned cnt = 0;
#pragma unroll
        for (int i = 0; i < 32; ++i)
            cnt += (unsigned)__popcll(__ballot(u[i] >= cand));
        if ((t & 63) == 0) wsum[b & 1][w] = cnt;
        __syncthreads();
        const unsigned tot = wsum[b & 1][0] + wsum[b & 1][1] +
                             wsum[b & 1][2] + wsum[b & 1][3];
        if (tot >= kp1) {
            thr = cand;
            if (tot == kp1) {
                unsigned m = 0xFFFFFFFFu;
#pragma unroll
                for (int i = 0; i < 32; ++i)
                    if (u[i] >= cand && u[i] < m) m = u[i];
#pragma unroll
                for (int off = 1; off < 64; off <<= 1) {
                    const unsigned o = __shfl_xor(m, off);
                    if (o < m) m = o;
                }
                if ((t & 63) == 0) wmin[w] = m;
                __syncthreads();
                unsigned mm = wmin[0];
                if (wmin[1] < mm) mm = wmin[1];
                if (wmin[2] < mm) mm = wmin[2];
                if (wmin[3] < mm) mm = wmin[3];
                teff = mm;
                done = true;
            }
        }
    }
    if (teff == 0) teff = thr;   // full-scan path: thr IS the kp1-th largest value

    // ---- fixup window ----
    unsigned hi_u, lo_u;
    if (thr != 0) {
        const float tf = __uint_as_float(teff);
        hi_u = __float_as_uint(tf + DELTA);
        const float lof = tf - DELTA;
        lo_u = (lof > 0.f) ? __float_as_uint(lof) : 0u;

        // count A = #(> hi) and gather window candidates
        unsigned acnt = 0;
#pragma unroll
        for (int q = 0; q < 32; ++q) {
            const unsigned uu = u[q];
            if (uu > hi_u) ++acnt;
            else if (uu != 0u && uu >= lo_u) {
                const int p = atomicAdd(&cnum, 1);
                if (p < MAXC) cidx[p] = (((q >> 2) * 256 + t) << 2) + (q & 3);
            }
        }
#pragma unroll
        for (int off = 1; off < 64; off <<= 1) acnt += __shfl_xor(acnt, off);
        if ((t & 63) == 0) wsum[0][w] = acnt;
        __syncthreads();
        const unsigned A = wsum[0][0] + wsum[0][1] + wsum[0][2] + wsum[0][3];
        const int nc = cnum < MAXC ? cnum : MAXC;

        // exact recompute: frozen serial fmaf chain, ascending k (== round-3 ordering)
        if (t < nc) {
            const float* rb = emb + (size_t)cidx[t] * DDIM;
            float a = 0.f;
#pragma unroll 8
            for (int k = 0; k < DDIM; ++k) a = fmaf(semb[k], rb[k], a);
            cval[t] = a;
        }
        __syncthreads();
        // rank among candidates (ties -> lower index wins, matching lax.top_k)
        if (t < nc) {
            const float e = cval[t];
            const int my = cidx[t];
            int r = 0;
            for (int d = 0; d < nc; ++d)
                r += (cval[d] > e) || (cval[d] == e && cidx[d] < my);
            if (A + (unsigned)r < kp1)
                atomicOr(&bitmap[my >> 5], 1u << (my & 31));
        }
        __syncthreads();
    } else {
        hi_u = 0u;            // fewer than kp1 positives: keep all positives
        lo_u = 0xFFFFFFFFu;   // disable candidate path
        __syncthreads();
    }

    // ---- write: keep certain-aboves and ranked-in candidates; zero the rest ----
#pragma unroll
    for (int i = 0; i < 8; ++i) {
        float4 o;
#pragma unroll
        for (int j = 0; j < 4; ++j) {
            const unsigned uu = u[i * 4 + j];
            const int idx = (i * 256 + t) * 4 + j;
            const bool keep = (uu > hi_u) ||
                              (uu != 0u && uu >= lo_u &&
                               ((bitmap[idx >> 5] >> (idx & 31)) & 1u));
            (&o.x)[j] = keep ? __uint_as_float(uu) : 0.f;
        }
        *(float4*)&rowp[(i * 256 + t) * 4] = o;
    }
}

extern "C" void kernel_launch(void* const* d_in, const int* in_sizes, int n_in,
                              void* d_out, int out_size, void* d_ws, size_t ws_size,
                              hipStream_t stream)
{
    const float* X  = (const float*)d_in[0];
    const float* W1 = (const float*)d_in[1];
    const float* b1 = (const float*)d_in[2];
    const float* W2 = (const float*)d_in[3];
    const float* b2 = (const float*)d_in[4];
    const int* kp1  = (const int*)d_in[5];
    float* out = (float*)d_out;
    float* emb = (float*)d_ws;   // 8192*128*4 = 4 MB scratch

    mlp_norm_kernel<<<512, 128, 0, stream>>>(X, W1, b1, W2, b2, emb, 16);
    simgemm_mfma<<<1024, 512, 0, stream>>>(emb, out);
    topk_relu_kernel<<<NN, 256, 0, stream>>>(out, emb, kp1);
}

// Round 9
// 276.002 us; speedup vs baseline: 1.4053x; 1.4053x over previous
//
#include <hip/hip_runtime.h>

#define NN 8192
#define DDIM 128
#define DELTA 0.0092f   // >= 2*delta_wc; delta_wc <= 2*2^-9*sum|a_i b_i| + accum ~ 4.0e-3
#define MAXC 256

typedef short short8 __attribute__((ext_vector_type(8)));
typedef float f32x16 __attribute__((ext_vector_type(16)));

__device__ __forceinline__ ushort bf16_rne(float v) {
    const unsigned x = __float_as_uint(v);
    return (ushort)((x + 0x7FFFu + ((x >> 16) & 1u)) >> 16);
}

// ---------------- Kernel 1: MLP (Linear->ReLU->Linear) + L2 normalize + bf16 copy ----
// f32 emb path FROZEN (bit-exact vs round-3/5 passing version); adds RNE bf16 mirror.
__global__ __launch_bounds__(128, 1)
void mlp_norm_kernel(const float* __restrict__ X, const float* __restrict__ W1,
                     const float* __restrict__ b1, const float* __restrict__ W2,
                     const float* __restrict__ b2, float* __restrict__ emb,
                     ushort* __restrict__ ebh, int rowsPerBlock)
{
    const int t = threadIdx.x;
    float4 w1r[32], w2r[32];
#pragma unroll
    for (int i = 0; i < 32; ++i) w1r[i] = *(const float4*)&W1[t * DDIM + i * 4];
#pragma unroll
    for (int i = 0; i < 32; ++i) w2r[i] = *(const float4*)&W2[t * DDIM + i * 4];
    const float bb1 = b1[t], bb2 = b2[t];

    __shared__ float sx[DDIM];
    __shared__ float sh[DDIM];
    __shared__ float wred[2];

    const int row0 = blockIdx.x * rowsPerBlock;
    for (int r = 0; r < rowsPerBlock; ++r) {
        const int row = row0 + r;
        sx[t] = X[(size_t)row * DDIM + t];
        __syncthreads();
        float acc = bb1;
#pragma unroll
        for (int i = 0; i < 32; ++i) {
            const float4 xv = *(const float4*)&sx[i * 4];
            acc = fmaf(xv.x, w1r[i].x, acc);
            acc = fmaf(xv.y, w1r[i].y, acc);
            acc = fmaf(xv.z, w1r[i].z, acc);
            acc = fmaf(xv.w, w1r[i].w, acc);
        }
        sh[t] = fmaxf(acc, 0.f);
        __syncthreads();
        float acc2 = bb2;
#pragma unroll
        for (int i = 0; i < 32; ++i) {
            const float4 hv = *(const float4*)&sh[i * 4];
            acc2 = fmaf(hv.x, w2r[i].x, acc2);
            acc2 = fmaf(hv.y, w2r[i].y, acc2);
            acc2 = fmaf(hv.z, w2r[i].z, acc2);
            acc2 = fmaf(hv.w, w2r[i].w, acc2);
        }
        float sq = acc2 * acc2;
#pragma unroll
        for (int off = 1; off < 64; off <<= 1) sq += __shfl_xor(sq, off);
        if ((t & 63) == 0) wred[t >> 6] = sq;
        __syncthreads();
        const float ss = wred[0] + wred[1];
        const float inv = 1.0f / fmaxf(sqrtf(ss), 1e-12f);
        const float v = acc2 * inv;
        emb[(size_t)row * DDIM + t] = v;
        ebh[(size_t)row * DDIM + t] = bf16_rne(v);
        __syncthreads();   // protect sx/sh/wred for next iteration
    }
}

// ---------------- Kernel 2: approx sim = ebh @ ebh^T (1-term bf16 MFMA, f32 acc) -----
// Store-wall-bound (256 MB). 128x128 tile, 256 threads = 4 waves (2x2), wave 64x64.
// K=128 staged entirely: LDS [128 rows][16 granules of 8 bf16], granule^(row&15) XOR
// swizzle on BOTH write and read (bank-verified even spread), single barrier, no K-loop.
__global__ __launch_bounds__(256)
void simgemm_bf16(const ushort* __restrict__ ebh, float* __restrict__ out)
{
    __shared__ ushort lA[128 * 128];
    __shared__ ushort lB[128 * 128];

    const int tid = threadIdx.x;
    const int bi = blockIdx.x & 63, bj = blockIdx.x >> 6;
    const int m0 = bi << 7, n0 = bj << 7;
    const int lane = tid & 63, wid = tid >> 6;
    const int wr = wid >> 1, wc = wid & 1;
    const int frow = lane & 31, fsel = lane >> 5;

    // stage: thread (row0 = tid>>4, granule g = tid&15) copies rows row0 + 16i.
    // global reads coalesced (16 lanes = 256B contiguous); LDS writes conflict-free.
    const int srow0 = tid >> 4, sg = tid & 15;
#pragma unroll
    for (int i = 0; i < 8; ++i) {
        const int row = srow0 + i * 16;
        const int so = row * 128 + ((sg ^ (row & 15)) << 3);
        *(uint4*)&lA[so] = *(const uint4*)&ebh[(size_t)(m0 + row) * DDIM + sg * 8];
        *(uint4*)&lB[so] = *(const uint4*)&ebh[(size_t)(n0 + row) * DDIM + sg * 8];
    }
    __syncthreads();

    f32x16 acc[2][2];
#pragma unroll
    for (int mb = 0; mb < 2; ++mb)
#pragma unroll
        for (int nb = 0; nb < 2; ++nb)
#pragma unroll
            for (int q = 0; q < 16; ++q) acc[mb][nb][q] = 0.f;

#pragma unroll
    for (int ks = 0; ks < 8; ++ks) {           // 8 k-steps of 16 cover K=128
        const int g = ks * 2 + fsel;           // granule of 8 bf16 along K
        short8 av[2], bv[2];
#pragma unroll
        for (int mb = 0; mb < 2; ++mb) {
            const int r = wr * 64 + mb * 32 + frow;
            av[mb] = *(const short8*)&lA[r * 128 + ((g ^ (r & 15)) << 3)];
        }
#pragma unroll
        for (int nb = 0; nb < 2; ++nb) {
            const int r = wc * 64 + nb * 32 + frow;
            bv[nb] = *(const short8*)&lB[r * 128 + ((g ^ (r & 15)) << 3)];
        }
#pragma unroll
        for (int mb = 0; mb < 2; ++mb)
#pragma unroll
            for (int nb = 0; nb < 2; ++nb)
                acc[mb][nb] = __builtin_amdgcn_mfma_f32_32x32x16_bf16(
                    av[mb], bv[nb], acc[mb][nb], 0, 0, 0);
    }

    // C/D layout: col = lane&31, row = (q&3) + 8*(q>>2) + 4*(lane>>5)  [verified r6/r7]
#pragma unroll
    for (int mb = 0; mb < 2; ++mb)
#pragma unroll
        for (int nb = 0; nb < 2; ++nb)
#pragma unroll
            for (int q = 0; q < 16; ++q) {
                const int rl = (q & 3) + 8 * (q >> 2) + 4 * fsel;
                const int grow = m0 + wr * 64 + mb * 32 + rl;
                const int gcol = n0 + wc * 64 + nb * 32 + (lane & 31);
                out[(size_t)grow * NN + gcol] = acc[mb][nb][q];
            }
}

// ---------------- Kernel 3: top-kp1 on approx sims + exact fixup + ReLU (in place) ----
// Radix-select kp1-th approx value t. a > t+DELTA certainly kept; a < t-DELTA certainly
// dropped (DELTA >= 2*worst-case approx error); window entries recomputed EXACTLY
// (frozen fmaf chain from f32 emb, == round-3-proven ordering) and ranked vs e*.
__global__ __launch_bounds__(256)
void topk_relu_kernel(float* __restrict__ out, const float* __restrict__ emb,
                      const int* __restrict__ kp1p)
{
    const int row = blockIdx.x;
    const int t = threadIdx.x;
    const int w = t >> 6;
    const unsigned kp1 = (unsigned)kp1p[0];
    float* rowp = out + (size_t)row * NN;

    __shared__ unsigned bitmap[NN / 32];   // 1 KB keep-bitmap for window candidates
    __shared__ float semb[DDIM];
    __shared__ unsigned wsum[2][4];
    __shared__ unsigned wmin[4];
    __shared__ int cidx[MAXC];
    __shared__ float cval[MAXC];
    __shared__ int cnum;

    bitmap[t] = 0;
    if (t == 0) cnum = 0;
    if (t < DDIM) semb[t] = emb[(size_t)row * DDIM + t];

    unsigned u[32];
#pragma unroll
    for (int i = 0; i < 8; ++i) {
        const float4 v = *(const float4*)&rowp[(i * 256 + t) * 4];
        u[i * 4 + 0] = v.x > 0.f ? __float_as_uint(v.x) : 0u;
        u[i * 4 + 1] = v.y > 0.f ? __float_as_uint(v.y) : 0u;
        u[i * 4 + 2] = v.z > 0.f ? __float_as_uint(v.z) : 0u;
        u[i * 4 + 3] = v.w > 0.f ? __float_as_uint(v.w) : 0u;
    }

    // ---- radix select kp1-th largest (approx), ballot+popcount, early exit ----
    unsigned thr = 0, teff = 0;
    bool done = false;
    for (int b = 29; b >= 0 && !done; --b) {
        const unsigned cand = thr | (1u << b);
        unsigned cnt = 0;
#pragma unroll
        for (int i = 0; i < 32; ++i)
            cnt += (unsigned)__popcll(__ballot(u[i] >= cand));
        if ((t & 63) == 0) wsum[b & 1][w] = cnt;
        __syncthreads();
        const unsigned tot = wsum[b & 1][0] + wsum[b & 1][1] +
                             wsum[b & 1][2] + wsum[b & 1][3];
        if (tot >= kp1) {
            thr = cand;
            if (tot == kp1) {
                unsigned m = 0xFFFFFFFFu;
#pragma unroll
                for (int i = 0; i < 32; ++i)
                    if (u[i] >= cand && u[i] < m) m = u[i];
#pragma unroll
                for (int off = 1; off < 64; off <<= 1) {
                    const unsigned o = __shfl_xor(m, off);
                    if (o < m) m = o;
                }
                if ((t & 63) == 0) wmin[w] = m;
                __syncthreads();
                unsigned mm = wmin[0];
                if (wmin[1] < mm) mm = wmin[1];
                if (wmin[2] < mm) mm = wmin[2];
                if (wmin[3] < mm) mm = wmin[3];
                teff = mm;
                done = true;
            }
        }
    }
    if (teff == 0) teff = thr;   // full-scan path: thr IS the kp1-th largest value

    // ---- fixup window ----
    unsigned hi_u, lo_u;
    if (thr != 0) {
        const float tf = __uint_as_float(teff);
        hi_u = __float_as_uint(tf + DELTA);
        const float lof = tf - DELTA;
        lo_u = (lof > 0.f) ? __float_as_uint(lof) : 0u;

        // A = #(approx > hi) certainly kept; gather window candidates
        unsigned acnt = 0;
#pragma unroll
        for (int q = 0; q < 32; ++q) {
            const unsigned uu = u[q];
            if (uu > hi_u) ++acnt;
            else if (uu != 0u && uu >= lo_u) {
                const int p = atomicAdd(&cnum, 1);
                if (p < MAXC) cidx[p] = (((q >> 2) * 256 + t) << 2) + (q & 3);
            }
        }
#pragma unroll
        for (int off = 1; off < 64; off <<= 1) acnt += __shfl_xor(acnt, off);
        if ((t & 63) == 0) wsum[0][w] = acnt;
        __syncthreads();
        const unsigned A = wsum[0][0] + wsum[0][1] + wsum[0][2] + wsum[0][3];
        const int nc = cnum < MAXC ? cnum : MAXC;

        // exact recompute: frozen serial fmaf chain, ascending k (== round-3 ordering)
        if (t < nc) {
            const float* rb = emb + (size_t)cidx[t] * DDIM;
            float a = 0.f;
#pragma unroll 8
            for (int k = 0; k < DDIM; ++k) a = fmaf(semb[k], rb[k], a);
            cval[t] = a;
        }
        __syncthreads();
        // rank among candidates (ties -> lower index wins, matching lax.top_k)
        if (t < nc) {
            const float e = cval[t];
            const int my = cidx[t];
            int r = 0;
            for (int d = 0; d < nc; ++d)
                r += (cval[d] > e) || (cval[d] == e && cidx[d] < my);
            if (A + (unsigned)r < kp1)
                atomicOr(&bitmap[my >> 5], 1u << (my & 31));
        }
        __syncthreads();
    } else {
        hi_u = 0u;            // fewer than kp1 positives: keep all positives
        lo_u = 0xFFFFFFFFu;   // disable candidate path
        __syncthreads();
    }

    // ---- write: keep certain-aboves and ranked-in candidates; zero the rest ----
#pragma unroll
    for (int i = 0; i < 8; ++i) {
        float4 o;
#pragma unroll
        for (int j = 0; j < 4; ++j) {
            const unsigned uu = u[i * 4 + j];
            const int idx = (i * 256 + t) * 4 + j;
            const bool keep = (uu > hi_u) ||
                              (uu != 0u && uu >= lo_u &&
                               ((bitmap[idx >> 5] >> (idx & 31)) & 1u));
            (&o.x)[j] = keep ? __uint_as_float(uu) : 0.f;
        }
        *(float4*)&rowp[(i * 256 + t) * 4] = o;
    }
}

extern "C" void kernel_launch(void* const* d_in, const int* in_sizes, int n_in,
                              void* d_out, int out_size, void* d_ws, size_t ws_size,
                              hipStream_t stream)
{
    const float* X  = (const float*)d_in[0];
    const float* W1 = (const float*)d_in[1];
    const float* b1 = (const float*)d_in[2];
    const float* W2 = (const float*)d_in[3];
    const float* b2 = (const float*)d_in[4];
    const int* kp1  = (const int*)d_in[5];
    float* out = (float*)d_out;
    float* emb  = (float*)d_ws;                                   // 4 MB f32
    ushort* ebh = (ushort*)((char*)d_ws + (size_t)NN * DDIM * 4); // 2 MB bf16

    mlp_norm_kernel<<<512, 128, 0, stream>>>(X, W1, b1, W2, b2, emb, ebh, 16);
    simgemm_bf16<<<4096, 256, 0, stream>>>(ebh, out);
    topk_relu_kernel<<<NN, 256, 0, stream>>>(out, emb, kp1);
}